// Round 2
// baseline (460.399 us; speedup 1.0000x reference)
//
#include <hip/hip_runtime.h>
#include <hip/hip_fp16.h>

// DeepLabV3 prototype-segmentation head, MI355X / gfx950.
// Pipeline: prep -> conv1(GEMM,f16 MFMA) -> conv2(+W-axis L2 fused) -> head(LN/L2/cos/max/LN) -> bicubic resize.
// All GEMM-ish stages: fp16 inputs, f32 accumulation via v_mfma_f32_32x32x16_f16.
// Workspace: 128.3 MB peak (outs aliases h1, which is dead after conv2).

typedef _Float16 f16;
typedef _Float16 f16x8 __attribute__((ext_vector_type(8)));
typedef float    f32x16 __attribute__((ext_vector_type(16)));

#define HW2   16384   // 128*128 pixels per batch image
#define NCLS  19
#define NPJ   192     // prototypes padded 190 -> 192

// ---------------- LDS swizzle: XOR the 16B slot index with low row bits ----------------
__device__ __forceinline__ int swz256(int row, int b) {           // 256B rows (128 fp16 / 64 f32)
  return row*256 + ((((b >> 4) ^ (row & 15)) << 4) | (b & 15));
}
__device__ __forceinline__ int swz512(int row, int b) {           // 512B rows (256 fp16)
  return row*512 + ((((b >> 4) ^ (row & 31)) << 4) | (b & 15));
}
__device__ __forceinline__ int swz128(int row, int b) {           // 128B rows (64 fp16)
  return row*128 + ((((b >> 4) ^ (row & 7)) << 4) | (b & 15));
}

// ---- reg-staged tile loaders: linear coalesced 16B global reads -> swizzled ds_write_b128 ----
__device__ __forceinline__ void stage256(const char* __restrict__ g, char* lds,
                                         long gstride, int niter, int wid, int nw, int lane) {
  int rin = lane >> 4, s = lane & 15;                 // 4 rows x 16 slots per issue
  for (int i = wid; i < niter; i += nw) {
    int r = i*4 + rin;
    uint4 v = *(const uint4*)(g + (long)r*gstride + s*16);
    *(uint4*)(lds + r*256 + ((s ^ (r & 15)) << 4)) = v;
  }
}
__device__ __forceinline__ void stage512(const char* __restrict__ g, char* lds,
                                         long gstride, int niter, int wid, int nw, int lane) {
  int rin = lane >> 5, s = lane & 31;                 // 2 rows x 32 slots per issue
  for (int i = wid; i < niter; i += nw) {
    int r = i*2 + rin;
    uint4 v = *(const uint4*)(g + (long)r*gstride + s*16);
    *(uint4*)(lds + r*512 + ((s ^ (r & 31)) << 4)) = v;
  }
}
__device__ __forceinline__ void stage128(const char* __restrict__ g, char* lds,
                                         long gstride, int niter, int wid, int nw, int lane) {
  int rin = lane >> 3, s = lane & 7;                  // 8 rows x 8 slots per issue
  for (int i = wid; i < niter; i += nw) {
    int r = i*8 + rin;
    uint4 v = *(const uint4*)(g + (long)r*gstride + s*16);
    *(uint4*)(lds + r*128 + ((s ^ (r & 7)) << 4)) = v;
  }
}

// =====================================================================================
// K0: prep — w1/w2 -> fp16 ; prototypes l2-normalized -> fp16 (rows 190,191 zero-padded)
// grid 704 x 64
// =====================================================================================
__global__ void k_prep(const float* __restrict__ w1, const float* __restrict__ w2,
                       const float* __restrict__ protos,
                       f16* __restrict__ w1h, f16* __restrict__ w2h, f16* __restrict__ prth)
{
  int b = blockIdx.x, l = threadIdx.x;
  if (b < 512) {
    const float* src = (b < 256) ? (w1 + (size_t)b*256) : (w2 + (size_t)(b-256)*256);
    f16* dst = (b < 256) ? (w1h + (size_t)b*256) : (w2h + (size_t)(b-256)*256);
    #pragma unroll
    for (int j = 0; j < 4; ++j) dst[l + 64*j] = (f16)src[l + 64*j];
  } else {
    int r = b - 512;                                   // 0..191
    if (r < 190) {
      float v[4]; float s = 0.f;
      #pragma unroll
      for (int j = 0; j < 4; ++j) { v[j] = protos[(size_t)r*256 + l + 64*j]; s += v[j]*v[j]; }
      #pragma unroll
      for (int m = 1; m < 64; m <<= 1) s += __shfl_xor(s, m);
      float sc = 1.f / fmaxf(sqrtf(s), 1e-12f);
      #pragma unroll
      for (int j = 0; j < 4; ++j) prth[(size_t)r*256 + l + 64*j] = (f16)(v[j]*sc);
    } else {
      #pragma unroll
      for (int j = 0; j < 4; ++j) prth[(size_t)r*256 + l + 64*j] = (f16)0.f;
    }
  }
}

// =====================================================================================
// K1/K2: GEMM  out[p][o] = act( sum_c A[p][c] * W[o][c] + bias[o] )
//   MODE 0 (conv1): A from x (f32 [c][p], transpose+cvt during staging), epilogue ReLU
//   MODE 1 (conv2): A from h1 (fp16 [p][c], linear staging), epilogue W-axis l2-normalize
// tile 128p x 128o, K=256 in two 128-chunks; 8 waves (512 thr), wave tile 64p x 32o,
// mfma_f32_32x32x16_f16, M_rep=2. grid 2048 = 8b * 128pt * 2ot (XCD-chunked).
// =====================================================================================
template<int MODE>
__global__ void __launch_bounds__(512, 4) k_conv(
    const float* __restrict__ xf, const f16* __restrict__ ah,
    const f16* __restrict__ wh,  const float* __restrict__ bias,
    f16* __restrict__ outh)
{
  __shared__ char smem[65536];
  char* As = smem;              // [128 p][128 c] fp16, 256B swizzled rows
  char* Bs = smem + 32768;      // [128 o][128 c] fp16

  // XCD de-swizzle: consecutive logical ids (which share the A tile) land on one XCD
  int bid = blockIdx.x;
  int logical = (bid & 7) * 256 + (bid >> 3);
  int b  = logical >> 8;
  int pt = (logical >> 1) & 127;
  int ot = logical & 1;
  int p0 = pt*128, o0 = ot*128;

  int tid = threadIdx.x, lane = tid & 63, wid = tid >> 6;
  int wp = wid >> 2, wn = wid & 3;

  f32x16 acc[2];
  #pragma unroll
  for (int m = 0; m < 2; ++m)
    #pragma unroll
    for (int r = 0; r < 16; ++r) acc[m][r] = 0.f;

  for (int cc = 0; cc < 2; ++cc) {
    int k0 = cc*128;
    if (MODE == 0) {
      // transpose+convert: read x[c][p0..p0+127] coalesced, scatter fp16 into [p][c]
      const float* xb = xf + ((size_t)b*256 + k0)*HW2 + p0;
      for (int i = wid; i < 128; i += 8) {
        float v0 = xb[(size_t)i*HW2 + lane];
        float v1 = xb[(size_t)i*HW2 + 64 + lane];
        *(f16*)(As + swz256(lane,      i*2)) = (f16)v0;
        *(f16*)(As + swz256(64 + lane, i*2)) = (f16)v1;
      }
    } else {
      const char* ab = (const char*)ah + ((size_t)(b*HW2 + p0)*256 + k0)*2;
      stage256(ab, As, 512, 32, wid, 8, lane);
    }
    {
      const char* wb = (const char*)wh + ((size_t)o0*256 + k0)*2;
      stage256(wb, Bs, 512, 32, wid, 8, lane);
    }
    __syncthreads();
    #pragma unroll
    for (int kk = 0; kk < 8; ++kk) {
      int byteK = kk*32 + (lane >> 5)*16;             // k = kk*16 + (lane>>5)*8 + e
      int colr = wn*32 + (lane & 31);
      f16x8 bf = *(const f16x8*)(Bs + swz256(colr, byteK));
      #pragma unroll
      for (int m = 0; m < 2; ++m) {
        int row = wp*64 + m*32 + (lane & 31);
        f16x8 af = *(const f16x8*)(As + swz256(row, byteK));
        acc[m] = __builtin_amdgcn_mfma_f32_32x32x16_f16(af, bf, acc[m], 0, 0, 0);
      }
    }
    __syncthreads();
  }

  int ocol = o0 + wn*32 + (lane & 31);
  float bv = bias[ocol];

  if (MODE == 0) {
    #pragma unroll
    for (int m = 0; m < 2; ++m)
      #pragma unroll
      for (int r = 0; r < 16; ++r) {
        int prow = wp*64 + m*32 + (r & 3) + 8*(r >> 2) + 4*(lane >> 5);   // D layout (m74/m101)
        float v = fmaxf(acc[m][r] + bv, 0.f);
        outh[((size_t)(b*HW2 + p0 + prow))*256 + ocol] = (f16)v;
      }
  } else {
    // bias, then l2-normalize along W: tile = exactly one image row (128 x-positions)
    float s = 0.f;
    #pragma unroll
    for (int m = 0; m < 2; ++m)
      #pragma unroll
      for (int r = 0; r < 16; ++r) { acc[m][r] += bv; s += acc[m][r]*acc[m][r]; }
    s += __shfl_xor(s, 32);                            // combine the two 4-row halves
    float* nb = (float*)smem;                          // alias A region (dead now): [2][128]
    if (lane < 32) nb[wp*128 + wn*32 + lane] = s;
    __syncthreads();
    float tot = nb[wn*32 + (lane & 31)] + nb[128 + wn*32 + (lane & 31)];
    float scale = 1.f / fmaxf(sqrtf(tot), 1e-12f);
    #pragma unroll
    for (int m = 0; m < 2; ++m)
      #pragma unroll
      for (int r = 0; r < 16; ++r) {
        int prow = wp*64 + m*32 + (r & 3) + 8*(r >> 2) + 4*(lane >> 5);
        outh[((size_t)(b*HW2 + p0 + prow))*256 + ocol] = (f16)(acc[m][r]*scale);
      }
  }
}

// =====================================================================================
// K3: head — per 64-pixel tile: LN(256)+L2 -> c ; c x protos^T MFMA -> masks[192];
//            max over 10 protos -> LN(19) -> out_small[b][k][p]
// 256 thr (4 waves). grid 2048 = 8b * 256 tiles.
// =====================================================================================
__global__ void __launch_bounds__(256, 2) k_head(
    const f16* __restrict__ hb, const float* __restrict__ ln1g, const float* __restrict__ ln1b,
    const f16* __restrict__ prth, const float* __restrict__ ln2g, const float* __restrict__ ln2b,
    float* __restrict__ outs)
{
  __shared__ char smem[64256];
  char* Ts = smem;                        // [64 p][512B] fp16 tile; later masks [192 j][256B] f32
  char* Ps = smem + 32768;                // protos chunk [192 j][128B] fp16
  float* Lg = (float*)(smem + 57344);
  float* Lb = (float*)(smem + 58368);
  float* Os = (float*)(smem + 59392);     // [19][64] f32

  int bid = blockIdx.x;
  int b = bid >> 8, pt = bid & 255;
  int p0 = pt*64;
  int tid = threadIdx.x, lane = tid & 63, wid = tid >> 6;

  stage512((const char*)hb + (size_t)(b*HW2 + p0)*512, Ts, 512, 32, wid, 4, lane);
  Lg[tid] = ln1g[tid];
  Lb[tid] = ln1b[tid];
  __syncthreads();

  // ---- per-pixel LayerNorm(256) + l2-normalize; 4 lanes per pixel ----
  int p = tid >> 2, q = tid & 3;
  f16x8 hreg[8];
  float sh = 0.f;
  #pragma unroll
  for (int j = 0; j < 8; ++j) {
    hreg[j] = *(const f16x8*)(Ts + swz512(p, q*128 + j*16));
    #pragma unroll
    for (int e = 0; e < 8; ++e) sh += (float)hreg[j][e];
  }
  sh += __shfl_xor(sh, 1); sh += __shfl_xor(sh, 2);
  float mu = sh * (1.f/256.f);
  float sv = 0.f;
  #pragma unroll
  for (int j = 0; j < 8; ++j)
    #pragma unroll
    for (int e = 0; e < 8; ++e) { float d = (float)hreg[j][e] - mu; sv += d*d; }
  sv += __shfl_xor(sv, 1); sv += __shfl_xor(sv, 2);
  float rstd = rsqrtf(sv*(1.f/256.f) + 1e-5f);
  float s2 = 0.f; f16x8 creg[8];
  #pragma unroll
  for (int j = 0; j < 8; ++j) {
    int ob = q*64 + j*8;
    #pragma unroll
    for (int e = 0; e < 8; ++e) {
      float c = ((float)hreg[j][e] - mu)*rstd*Lg[ob+e] + Lb[ob+e];
      s2 += c*c; creg[j][e] = (f16)c;
    }
  }
  s2 += __shfl_xor(s2, 1); s2 += __shfl_xor(s2, 2);
  float scale = 1.f / fmaxf(sqrtf(s2), 1e-12f);
  #pragma unroll
  for (int j = 0; j < 8; ++j) {
    f16x8 w;
    #pragma unroll
    for (int e = 0; e < 8; ++e) w[e] = (f16)((float)creg[j][e]*scale);
    *(f16x8*)(Ts + swz512(p, q*128 + j*16)) = w;
  }
  __syncthreads();

  // ---- MFMA: [64 p] x [192 protos], K=256 in four 64-chunks ----
  int wj = wid & 1, wp2 = wid >> 1;                    // 2 j-waves x 2 p-waves
  f32x16 acc[3];
  #pragma unroll
  for (int n = 0; n < 3; ++n)
    #pragma unroll
    for (int r = 0; r < 16; ++r) acc[n][r] = 0.f;

  for (int cci = 0; cci < 4; ++cci) {
    stage128((const char*)prth + (size_t)cci*128, Ps, 512, 24, wid, 4, lane);
    __syncthreads();
    #pragma unroll
    for (int kk = 0; kk < 4; ++kk) {
      int row = wp2*32 + (lane & 31);
      f16x8 af = *(const f16x8*)(Ts + swz512(row, cci*128 + kk*32 + (lane>>5)*16));
      #pragma unroll
      for (int n = 0; n < 3; ++n) {
        int col = wj*96 + n*32 + (lane & 31);
        f16x8 bf = *(const f16x8*)(Ps + swz128(col, kk*32 + (lane>>5)*16));
        acc[n] = __builtin_amdgcn_mfma_f32_32x32x16_f16(af, bf, acc[n], 0, 0, 0);
      }
    }
    __syncthreads();
  }

  // ---- masks to LDS [192 j][64 p] f32 (overlays Ts/Ps, all MFMA done) ----
  #pragma unroll
  for (int n = 0; n < 3; ++n) {
    int col = wj*96 + n*32 + (lane & 31);
    #pragma unroll
    for (int r = 0; r < 16; ++r) {
      int prow = wp2*32 + (r & 3) + 8*(r >> 2) + 4*(lane >> 5);
      *(float*)(Ts + swz256(col, prow*4)) = acc[n][r];
    }
  }
  __syncthreads();

  // ---- max over 10 prototypes + LayerNorm(19); 4 lanes per pixel ----
  {
    int pp = tid >> 2, ql = tid & 3;
    float mx[5]; float ssum = 0.f;
    #pragma unroll
    for (int ki = 0; ki < 5; ++ki) {
      int k = ql + 4*ki;
      float m = 0.f;
      if (k < NCLS) {
        m = -1e30f;
        #pragma unroll
        for (int mm = 0; mm < 10; ++mm)
          m = fmaxf(m, *(const float*)(Ts + swz256(k*10 + mm, pp*4)));
        ssum += m;
      }
      mx[ki] = m;
    }
    ssum += __shfl_xor(ssum, 1); ssum += __shfl_xor(ssum, 2);
    float mu2 = ssum * (1.f/19.f);
    float sv2 = 0.f;
    #pragma unroll
    for (int ki = 0; ki < 5; ++ki) {
      int k = ql + 4*ki;
      if (k < NCLS) { float d = mx[ki]-mu2; sv2 += d*d; }
    }
    sv2 += __shfl_xor(sv2, 1); sv2 += __shfl_xor(sv2, 2);
    float rstd2 = rsqrtf(sv2*(1.f/19.f) + 1e-5f);
    #pragma unroll
    for (int ki = 0; ki < 5; ++ki) {
      int k = ql + 4*ki;
      if (k < NCLS) Os[k*64 + pp] = (mx[ki]-mu2)*rstd2*ln2g[k] + ln2b[k];
    }
  }
  __syncthreads();
  for (int idx = tid; idx < NCLS*64; idx += 256) {
    int k = idx >> 6, pp = idx & 63;
    outs[((size_t)b*NCLS + k)*HW2 + p0 + pp] = Os[idx];
  }
}

// =====================================================================================
// K4: bicubic 4x upsample (jax.image.resize 'cubic': Keys a=-0.5, half-pixel grid,
// truncated-kernel renormalization at borders). Separable with 5-row register window.
// grid 1216 = (8*19 channels) * 8 y-slabs; 256 thr (each owns 2 output columns).
// =====================================================================================
__device__ __forceinline__ float kcub(float t) {       // t >= 0
  if (t >= 2.f) return 0.f;
  if (t >= 1.f) return ((-0.5f*t + 2.5f)*t - 4.f)*t + 2.f;
  return ((1.5f*t - 2.5f)*t)*t + 1.f;
}

__global__ void __launch_bounds__(256) k_resize(const float* __restrict__ outs,
                                                float* __restrict__ out)
{
  int ch = blockIdx.x >> 3, slab = blockIdx.x & 7;
  const float* src = outs + (size_t)ch*HW2;
  float* dst = out + (size_t)ch*262144;
  __shared__ float rows[20*128];
  __shared__ float wyt[64][4];
  int tid = threadIdx.x;

  int r0 = slab*16 - 2; if (r0 < 0) r0 = 0;
  int r1 = slab*16 + 17; if (r1 > 127) r1 = 127;
  int nr = r1 - r0 + 1;
  for (int idx = tid; idx < nr*128; idx += 256) rows[idx] = src[r0*128 + idx];

  if (tid < 64) {
    int y = slab*64 + tid;
    float s = y*0.25f - 0.375f;
    float jf = floorf(s); int j = (int)jf; float f = s - jf;
    float w[4] = { kcub(1.f+f), kcub(f), kcub(1.f-f), kcub(2.f-f) };
    float ws = 0.f;
    #pragma unroll
    for (int k = 0; k < 4; ++k) { int t = j-1+k; if (t < 0 || t > 127) w[k] = 0.f; ws += w[k]; }
    float inv = 1.f/ws;
    #pragma unroll
    for (int k = 0; k < 4; ++k) wyt[tid][k] = w[k]*inv;
  }
  __syncthreads();

  // per-thread x-weights for columns tid and tid+256
  float wx[2][4]; int tx[2][4];
  #pragma unroll
  for (int cI = 0; cI < 2; ++cI) {
    int xc = tid + cI*256;
    float s = xc*0.25f - 0.375f;
    float jf = floorf(s); int j = (int)jf; float f = s - jf;
    float w[4] = { kcub(1.f+f), kcub(f), kcub(1.f-f), kcub(2.f-f) };
    float ws = 0.f;
    #pragma unroll
    for (int k = 0; k < 4; ++k) { int t = j-1+k; if (t < 0 || t > 127) w[k] = 0.f; ws += w[k]; }
    #pragma unroll
    for (int k = 0; k < 4; ++k) {
      wx[cI][k] = w[k]/ws;
      int t = j-1+k; tx[cI][k] = t < 0 ? 0 : (t > 127 ? 127 : t);
    }
  }

  auto rowdot = [&](int cI, int absrow) -> float {
    int rr = absrow < 0 ? 0 : (absrow > 127 ? 127 : absrow);
    const float* rp = rows + (rr - r0)*128;
    return wx[cI][0]*rp[tx[cI][0]] + wx[cI][1]*rp[tx[cI][1]]
         + wx[cI][2]*rp[tx[cI][2]] + wx[cI][3]*rp[tx[cI][3]];
  };

  int base = slab*16;
  // 5-row sliding window, all-static register refs (rule #20 safe)
  float a0 = rowdot(0, base-2), a1 = rowdot(0, base-1), a2 = rowdot(0, base),   a3 = rowdot(0, base+1);
  float b0 = rowdot(1, base-2), b1 = rowdot(1, base-1), b2 = rowdot(1, base),   b3 = rowdot(1, base+1);

  for (int m = 0; m < 16; ++m) {
    float na = rowdot(0, base + m + 2);
    float nb2 = rowdot(1, base + m + 2);
    int y0 = m*4;
    // y = 4m, 4m+1 use rows (m-2..m+1); y = 4m+2, 4m+3 use rows (m-1..m+2)
    {
      float w0 = wyt[y0][0],   w1 = wyt[y0][1],   w2 = wyt[y0][2],   w3 = wyt[y0][3];
      size_t ob = ((size_t)(slab*64 + y0))*512;
      dst[ob + tid]       = w0*a0 + w1*a1 + w2*a2 + w3*a3;
      dst[ob + tid + 256] = w0*b0 + w1*b1 + w2*b2 + w3*b3;
    }
    {
      float w0 = wyt[y0+1][0], w1 = wyt[y0+1][1], w2 = wyt[y0+1][2], w3 = wyt[y0+1][3];
      size_t ob = ((size_t)(slab*64 + y0 + 1))*512;
      dst[ob + tid]       = w0*a0 + w1*a1 + w2*a2 + w3*a3;
      dst[ob + tid + 256] = w0*b0 + w1*b1 + w2*b2 + w3*b3;
    }
    {
      float w0 = wyt[y0+2][0], w1 = wyt[y0+2][1], w2 = wyt[y0+2][2], w3 = wyt[y0+2][3];
      size_t ob = ((size_t)(slab*64 + y0 + 2))*512;
      dst[ob + tid]       = w0*a1 + w1*a2 + w2*a3 + w3*na;
      dst[ob + tid + 256] = w0*b1 + w1*b2 + w2*b3 + w3*nb2;
    }
    {
      float w0 = wyt[y0+3][0], w1 = wyt[y0+3][1], w2 = wyt[y0+3][2], w3 = wyt[y0+3][3];
      size_t ob = ((size_t)(slab*64 + y0 + 3))*512;
      dst[ob + tid]       = w0*a1 + w1*a2 + w2*a3 + w3*na;
      dst[ob + tid + 256] = w0*b1 + w1*b2 + w2*b3 + w3*nb2;
    }
    a0 = a1; a1 = a2; a2 = a3; a3 = na;
    b0 = b1; b1 = b2; b2 = b3; b3 = nb2;
  }
}

// =====================================================================================
extern "C" void kernel_launch(void* const* d_in, const int* in_sizes, int n_in,
                              void* d_out, int out_size, void* d_ws, size_t ws_size,
                              hipStream_t stream) {
  (void)in_sizes; (void)n_in; (void)out_size; (void)ws_size;
  const float* x    = (const float*)d_in[0];
  const float* w1   = (const float*)d_in[1];
  const float* b1   = (const float*)d_in[2];
  const float* w2   = (const float*)d_in[3];
  const float* b2   = (const float*)d_in[4];
  const float* ln1g = (const float*)d_in[5];
  const float* ln1b = (const float*)d_in[6];
  const float* ln2g = (const float*)d_in[7];
  const float* ln2b = (const float*)d_in[8];
  const float* prot = (const float*)d_in[9];
  float* out = (float*)d_out;
  char* ws = (char*)d_ws;

  // workspace layout (peak 134578176 B ~= 128.3 MB)
  f16*   w1h  = (f16*)(ws + 0);                  //   131072 B
  f16*   w2h  = (f16*)(ws + 131072);             //   131072 B
  f16*   prth = (f16*)(ws + 262144);             //    98304 B (192x256 fp16)
  f16*   h1   = (f16*)(ws + 360448);             // 67108864 B  [8][16384][256] fp16
  f16*   hb   = (f16*)(ws + 67469312);           // 67108864 B  normalized features
  float* outs = (float*)(ws + 360448);           //  9961472 B  [8][19][16384] f32 — ALIASES h1 (dead after conv2)

  k_prep  <<<dim3(704),  dim3(64),  0, stream>>>(w1, w2, prot, w1h, w2h, prth);
  k_conv<0><<<dim3(2048), dim3(512), 0, stream>>>(x, (const f16*)nullptr, w1h, b1, h1);
  k_conv<1><<<dim3(2048), dim3(512), 0, stream>>>((const float*)nullptr, h1, w2h, b2, hb);
  k_head  <<<dim3(2048), dim3(256), 0, stream>>>(hb, ln1g, ln1b, prth, ln2g, ln2b, outs);
  k_resize<<<dim3(1216), dim3(256), 0, stream>>>(outs, out);
}

// Round 4
// 401.499 us; speedup vs baseline: 1.1467x; 1.1467x over previous
//
#include <hip/hip_runtime.h>
#include <hip/hip_fp16.h>

// DeepLabV3 prototype-segmentation head, MI355X / gfx950.
// Round 4 == round 3 resubmit (GPU acquisition timeout, kernel never ran).
// FUSED conv1+conv2+head into one row-resident kernel (one block = one
// image row x all 256 channels). Deletes h1/hb HBM round-trips (-256 MB).
// Pipeline: prep -> fused(conv1->relu->conv2->W-L2->LN256->L2->protoGEMM->max->LN19) -> resize.

typedef _Float16 f16;
typedef _Float16 f16x4 __attribute__((ext_vector_type(4)));
typedef _Float16 f16x8 __attribute__((ext_vector_type(8)));
typedef float    f32x16 __attribute__((ext_vector_type(16)));

#define HW2   16384   // 128*128 pixels per image
#define NCLS  19

// ---------------- LDS swizzles: XOR the 16B slot index with low row bits ----------------
__device__ __forceinline__ int swz128(int row, int b) {           // 128B rows (64 fp16)
  return row*128 + ((((b >> 4) ^ (row & 7)) << 4) | (b & 15));
}
__device__ __forceinline__ int swz512(int row, int b) {           // 512B rows (256 fp16 / 128 f32)
  return row*512 + ((((b >> 4) ^ (row & 31)) << 4) | (b & 15));
}

// linear 16B global reads -> swizzled ds_write_b128 into 128B rows
__device__ __forceinline__ void stage128(const char* __restrict__ g, char* lds,
                                         long gstride, int niter, int wid, int nw, int lane) {
  int rin = lane >> 3, s = lane & 7;                  // 8 rows x 8 slots per issue
  for (int i = wid; i < niter; i += nw) {
    int r = i*8 + rin;
    uint4 v = *(const uint4*)(g + (long)r*gstride + s*16);
    *(uint4*)(lds + r*128 + ((s ^ (r & 7)) << 4)) = v;
  }
}

// =====================================================================================
// K0: prep — w1/w2 -> fp16 ; prototypes l2-normalized -> fp16 (rows 190,191 zero)
// grid 704 x 64
// =====================================================================================
__global__ void k_prep(const float* __restrict__ w1, const float* __restrict__ w2,
                       const float* __restrict__ protos,
                       f16* __restrict__ w1h, f16* __restrict__ w2h, f16* __restrict__ prth)
{
  int b = blockIdx.x, l = threadIdx.x;
  if (b < 512) {
    const float* src = (b < 256) ? (w1 + (size_t)b*256) : (w2 + (size_t)(b-256)*256);
    f16* dst = (b < 256) ? (w1h + (size_t)b*256) : (w2h + (size_t)(b-256)*256);
    #pragma unroll
    for (int j = 0; j < 4; ++j) dst[l + 64*j] = (f16)src[l + 64*j];
  } else {
    int r = b - 512;                                   // 0..191
    if (r < 190) {
      float v[4]; float s = 0.f;
      #pragma unroll
      for (int j = 0; j < 4; ++j) { v[j] = protos[(size_t)r*256 + l + 64*j]; s += v[j]*v[j]; }
      #pragma unroll
      for (int m = 1; m < 64; m <<= 1) s += __shfl_xor(s, m);
      float sc = 1.f / fmaxf(sqrtf(s), 1e-12f);
      #pragma unroll
      for (int j = 0; j < 4; ++j) prth[(size_t)r*256 + l + 64*j] = (f16)(v[j]*sc);
    } else {
      #pragma unroll
      for (int j = 0; j < 4; ++j) prth[(size_t)r*256 + l + 64*j] = (f16)0.f;
    }
  }
}

// =====================================================================================
// K1: FUSED row kernel. Block = (image b, row h): 128 pixels x full channel range.
// 512 thr (8 waves). LDS 112 KB -> 1 block/CU.
//   LDS map:  As  @0      16KB  [128 p][64 c]  fp16 x-chunk (transposed)   | later: nbuf/Lg/Lb | masks
//             Bs  @16384  32KB  [256 o][64 c]  fp16 W chunk / proto chunk  | masks
//             H   @49152  64KB  [128 p][256 ch] fp16 (h1, then h2, then c) | masks head / Os
//   masks @0  96KB [192 j][128 p] f32 (after proto MFMA, everything above is dead)
//   Os @98304 9.7KB [19][128] f32
// =====================================================================================
__global__ void __launch_bounds__(512, 1) k_fused(
    const float* __restrict__ xf,
    const f16* __restrict__ w1h, const float* __restrict__ b1g,
    const f16* __restrict__ w2h, const float* __restrict__ b2g,
    const float* __restrict__ ln1g, const float* __restrict__ ln1b,
    const f16* __restrict__ prth, const float* __restrict__ ln2g, const float* __restrict__ ln2b,
    float* __restrict__ outs)
{
  __shared__ char smem[114688];
  char* As = smem;
  char* Bs = smem + 16384;
  char* H  = smem + 49152;
  float* nbuf = (float*)smem;             // [2][256] f32 (W-L2 partials)
  float* Lg   = (float*)(smem + 4096);    // [256]
  float* Lb   = (float*)(smem + 5120);    // [256]
  float* Os   = (float*)(smem + 98304);   // [19][128]

  int bid = blockIdx.x;
  int b = bid >> 7, pt = bid & 127;       // image, row
  int tid = threadIdx.x, lane = tid & 63, wid = tid >> 6;
  int hi = lane >> 5, l31 = lane & 31;
  int wp = wid >> 2, wn = wid & 3;        // conv wave grid: 2p x 4o (64p x 64o tiles)

  f32x16 acc[2][2];
  #pragma unroll
  for (int m = 0; m < 2; ++m)
    #pragma unroll
    for (int n = 0; n < 2; ++n)
      #pragma unroll
      for (int r = 0; r < 16; ++r) acc[m][n][r] = 0.f;

  // ================= conv1: h1[128p][256o] = relu(X * W1^T + b1) =================
  for (int cc = 0; cc < 4; ++cc) {
    __syncthreads();
    { // x transpose-stage: thread = (cg 0..15, pg 0..31): float4 loads, f16x4 LDS writes
      int cg = tid >> 5, pg = tid & 31;
      const float* xb = xf + ((size_t)(b*256 + cc*64 + cg*4))*HW2 + pt*128 + pg*4;
      float4 v0 = *(const float4*)(xb);
      float4 v1 = *(const float4*)(xb + HW2);
      float4 v2 = *(const float4*)(xb + 2*HW2);
      float4 v3 = *(const float4*)(xb + 3*HW2);
      #define PUT(rr, c0, c1, c2, c3) { f16x4 h4 = { (f16)(c0), (f16)(c1), (f16)(c2), (f16)(c3) }; \
        *(f16x4*)(As + swz128(pg*4 + rr, cg*8)) = h4; }
      PUT(0, v0.x, v1.x, v2.x, v3.x)
      PUT(1, v0.y, v1.y, v2.y, v3.y)
      PUT(2, v0.z, v1.z, v2.z, v3.z)
      PUT(3, v0.w, v1.w, v2.w, v3.w)
      #undef PUT
    }
    stage128((const char*)w1h + cc*128, Bs, 512, 32, wid, 8, lane);
    __syncthreads();
    #pragma unroll
    for (int kk = 0; kk < 4; ++kk) {
      int byteK = kk*32 + hi*16;
      f16x8 a0 = *(const f16x8*)(As + swz128(wp*64 +      l31, byteK));
      f16x8 a1 = *(const f16x8*)(As + swz128(wp*64 + 32 + l31, byteK));
      f16x8 b0 = *(const f16x8*)(Bs + swz128(wn*64 +      l31, byteK));
      f16x8 b1 = *(const f16x8*)(Bs + swz128(wn*64 + 32 + l31, byteK));
      acc[0][0] = __builtin_amdgcn_mfma_f32_32x32x16_f16(a0, b0, acc[0][0], 0, 0, 0);
      acc[0][1] = __builtin_amdgcn_mfma_f32_32x32x16_f16(a0, b1, acc[0][1], 0, 0, 0);
      acc[1][0] = __builtin_amdgcn_mfma_f32_32x32x16_f16(a1, b0, acc[1][0], 0, 0, 0);
      acc[1][1] = __builtin_amdgcn_mfma_f32_32x32x16_f16(a1, b1, acc[1][1], 0, 0, 0);
    }
  }
  __syncthreads();
  // epilogue: bias + relu -> H fp16 [128p][256o] (swz512 rows; scatter is 2-way/free)
  #pragma unroll
  for (int n = 0; n < 2; ++n) {
    int o = wn*64 + n*32 + l31;
    float bv = b1g[o];
    #pragma unroll
    for (int m = 0; m < 2; ++m)
      #pragma unroll
      for (int r = 0; r < 16; ++r) {
        int p = wp*64 + m*32 + (r & 3) + 8*(r >> 2) + 4*hi;
        *(f16*)(H + swz512(p, o*2)) = (f16)fmaxf(acc[m][n][r] + bv, 0.f);
      }
  }

  // ================= conv2: h2[128p][256o] = h1 * W2^T + b2 =================
  #pragma unroll
  for (int m = 0; m < 2; ++m)
    #pragma unroll
    for (int n = 0; n < 2; ++n)
      #pragma unroll
      for (int r = 0; r < 16; ++r) acc[m][n][r] = 0.f;

  for (int cc = 0; cc < 4; ++cc) {
    __syncthreads();                       // H writes visible / prev Bs reads done
    stage128((const char*)w2h + cc*128, Bs, 512, 32, wid, 8, lane);
    __syncthreads();
    #pragma unroll
    for (int kk = 0; kk < 4; ++kk) {
      int byteC = cc*128 + kk*32 + hi*16;
      int byteK = kk*32 + hi*16;
      f16x8 a0 = *(const f16x8*)(H + swz512(wp*64 +      l31, byteC));
      f16x8 a1 = *(const f16x8*)(H + swz512(wp*64 + 32 + l31, byteC));
      f16x8 b0 = *(const f16x8*)(Bs + swz128(wn*64 +      l31, byteK));
      f16x8 b1 = *(const f16x8*)(Bs + swz128(wn*64 + 32 + l31, byteK));
      acc[0][0] = __builtin_amdgcn_mfma_f32_32x32x16_f16(a0, b0, acc[0][0], 0, 0, 0);
      acc[0][1] = __builtin_amdgcn_mfma_f32_32x32x16_f16(a0, b1, acc[0][1], 0, 0, 0);
      acc[1][0] = __builtin_amdgcn_mfma_f32_32x32x16_f16(a1, b0, acc[1][0], 0, 0, 0);
      acc[1][1] = __builtin_amdgcn_mfma_f32_32x32x16_f16(a1, b1, acc[1][1], 0, 0, 0);
    }
  }
  __syncthreads();                         // all conv2 H-reads done

  // ---- bias2 + W-axis L2 (norm over the 128 pixels, per channel o) ----
  float sn[2];
  #pragma unroll
  for (int n = 0; n < 2; ++n) {
    int o = wn*64 + n*32 + l31;
    float bv = b2g[o];
    float s = 0.f;
    #pragma unroll
    for (int m = 0; m < 2; ++m)
      #pragma unroll
      for (int r = 0; r < 16; ++r) { acc[m][n][r] += bv; s += acc[m][n][r]*acc[m][n][r]; }
    s += __shfl_xor(s, 32);                // combine hi halves (same o, disjoint p)
    sn[n] = s;
  }
  if (lane < 32) {
    nbuf[wp*256 + wn*64 +      lane] = sn[0];
    nbuf[wp*256 + wn*64 + 32 + lane] = sn[1];
  }
  if (tid < 256) { Lg[tid] = ln1g[tid]; Lb[tid] = ln1b[tid]; }
  __syncthreads();
  #pragma unroll
  for (int n = 0; n < 2; ++n) {
    int o = wn*64 + n*32 + l31;
    float tot = nbuf[o] + nbuf[256 + o];
    float sc = 1.f / fmaxf(sqrtf(tot), 1e-12f);
    #pragma unroll
    for (int m = 0; m < 2; ++m)
      #pragma unroll
      for (int r = 0; r < 16; ++r) {
        int p = wp*64 + m*32 + (r & 3) + 8*(r >> 2) + 4*hi;
        *(f16*)(H + swz512(p, o*2)) = (f16)(acc[m][n][r]*sc);
      }
  }
  __syncthreads();

  // ---- per-pixel LayerNorm(256) + l2-normalize (4 lanes per pixel) ----
  {
    int p = tid >> 2, q = tid & 3;
    f16x8 hreg[8];
    float sh = 0.f;
    #pragma unroll
    for (int j = 0; j < 8; ++j) {
      hreg[j] = *(const f16x8*)(H + swz512(p, q*128 + j*16));
      #pragma unroll
      for (int e = 0; e < 8; ++e) sh += (float)hreg[j][e];
    }
    sh += __shfl_xor(sh, 1); sh += __shfl_xor(sh, 2);
    float mu = sh * (1.f/256.f);
    float sv = 0.f;
    #pragma unroll
    for (int j = 0; j < 8; ++j)
      #pragma unroll
      for (int e = 0; e < 8; ++e) { float d = (float)hreg[j][e] - mu; sv += d*d; }
    sv += __shfl_xor(sv, 1); sv += __shfl_xor(sv, 2);
    float rstd = rsqrtf(sv*(1.f/256.f) + 1e-5f);
    float s2 = 0.f; f16x8 creg[8];
    #pragma unroll
    for (int j = 0; j < 8; ++j) {
      int ob = q*64 + j*8;
      #pragma unroll
      for (int e = 0; e < 8; ++e) {
        float c = ((float)hreg[j][e] - mu)*rstd*Lg[ob+e] + Lb[ob+e];
        s2 += c*c; creg[j][e] = (f16)c;
      }
    }
    s2 += __shfl_xor(s2, 1); s2 += __shfl_xor(s2, 2);
    float scale = 1.f / fmaxf(sqrtf(s2), 1e-12f);
    #pragma unroll
    for (int j = 0; j < 8; ++j) {
      f16x8 w;
      #pragma unroll
      for (int e = 0; e < 8; ++e) w[e] = (f16)((float)creg[j][e]*scale);
      *(f16x8*)(H + swz512(p, q*128 + j*16)) = w;
    }
  }

  // ================= proto GEMM: masks[192 j][128 p] = c x protos^T =================
  int wj = wid & 1, wp2 = wid >> 1;        // 2 j-waves x 4 p-waves (32p x 96j per wave)
  f32x16 am[3];
  #pragma unroll
  for (int n = 0; n < 3; ++n)
    #pragma unroll
    for (int r = 0; r < 16; ++r) am[n][r] = 0.f;

  for (int cci = 0; cci < 4; ++cci) {
    __syncthreads();
    stage128((const char*)prth + cci*128, Bs, 512, 24, wid, 8, lane);
    __syncthreads();
    #pragma unroll
    for (int kk = 0; kk < 4; ++kk) {
      int byteC = cci*128 + kk*32 + hi*16;
      int byteK = kk*32 + hi*16;
      f16x8 af = *(const f16x8*)(H + swz512(wp2*32 + l31, byteC));
      #pragma unroll
      for (int n = 0; n < 3; ++n) {
        f16x8 bf = *(const f16x8*)(Bs + swz128(wj*96 + n*32 + l31, byteK));
        am[n] = __builtin_amdgcn_mfma_f32_32x32x16_f16(af, bf, am[n], 0, 0, 0);
      }
    }
  }
  __syncthreads();                         // all proto MFMA done; LDS free for masks

  // masks scatter: [192 j][128 p] f32, swz512 rows @ smem+0
  #pragma unroll
  for (int n = 0; n < 3; ++n) {
    int j = wj*96 + n*32 + l31;
    #pragma unroll
    for (int r = 0; r < 16; ++r) {
      int p = wp2*32 + (r & 3) + 8*(r >> 2) + 4*hi;
      *(float*)(smem + swz512(j, p*4)) = am[n][r];
    }
  }
  __syncthreads();

  // ---- max over 10 prototypes + LayerNorm(19) (4 lanes per pixel) ----
  {
    int pp = tid >> 2, ql = tid & 3;
    float mx[5]; float ssum = 0.f;
    #pragma unroll
    for (int ki = 0; ki < 5; ++ki) {
      int k = ql + 4*ki;
      float m = 0.f;
      if (k < NCLS) {
        m = -1e30f;
        #pragma unroll
        for (int mm = 0; mm < 10; ++mm)
          m = fmaxf(m, *(const float*)(smem + swz512(k*10 + mm, pp*4)));
        ssum += m;
      }
      mx[ki] = m;
    }
    ssum += __shfl_xor(ssum, 1); ssum += __shfl_xor(ssum, 2);
    float mu2 = ssum * (1.f/19.f);
    float sv2 = 0.f;
    #pragma unroll
    for (int ki = 0; ki < 5; ++ki) {
      int k = ql + 4*ki;
      if (k < NCLS) { float d = mx[ki]-mu2; sv2 += d*d; }
    }
    sv2 += __shfl_xor(sv2, 1); sv2 += __shfl_xor(sv2, 2);
    float rstd2 = rsqrtf(sv2*(1.f/19.f) + 1e-5f);
    #pragma unroll
    for (int ki = 0; ki < 5; ++ki) {
      int k = ql + 4*ki;
      if (k < NCLS) Os[k*128 + pp] = (mx[ki]-mu2)*rstd2*ln2g[k] + ln2b[k];
    }
  }
  __syncthreads();
  for (int idx = tid; idx < NCLS*128; idx += 512) {
    int k = idx >> 7, pp = idx & 127;
    outs[((size_t)b*NCLS + k)*HW2 + pt*128 + pp] = Os[idx];
  }
}

// =====================================================================================
// K2: bicubic 4x upsample (jax cubic: Keys a=-0.5, half-pixel, border renormalization).
// grid 1216 = (8*19 ch) * 8 y-slabs; 256 thr (each owns 2 output columns).
// =====================================================================================
__device__ __forceinline__ float kcub(float t) {       // t >= 0
  if (t >= 2.f) return 0.f;
  if (t >= 1.f) return ((-0.5f*t + 2.5f)*t - 4.f)*t + 2.f;
  return ((1.5f*t - 2.5f)*t)*t + 1.f;
}

__global__ void __launch_bounds__(256) k_resize(const float* __restrict__ outs,
                                                float* __restrict__ out)
{
  int ch = blockIdx.x >> 3, slab = blockIdx.x & 7;
  const float* src = outs + (size_t)ch*HW2;
  float* dst = out + (size_t)ch*262144;
  __shared__ float rows[20*128];
  __shared__ float wyt[64][4];
  int tid = threadIdx.x;

  int r0 = slab*16 - 2; if (r0 < 0) r0 = 0;
  int r1 = slab*16 + 17; if (r1 > 127) r1 = 127;
  int nr = r1 - r0 + 1;
  for (int idx = tid; idx < nr*128; idx += 256) rows[idx] = src[r0*128 + idx];

  if (tid < 64) {
    int y = slab*64 + tid;
    float s = y*0.25f - 0.375f;
    float jf = floorf(s); int j = (int)jf; float f = s - jf;
    float w[4] = { kcub(1.f+f), kcub(f), kcub(1.f-f), kcub(2.f-f) };
    float ws = 0.f;
    #pragma unroll
    for (int k = 0; k < 4; ++k) { int t = j-1+k; if (t < 0 || t > 127) w[k] = 0.f; ws += w[k]; }
    float inv = 1.f/ws;
    #pragma unroll
    for (int k = 0; k < 4; ++k) wyt[tid][k] = w[k]*inv;
  }
  __syncthreads();

  float wx[2][4]; int tx[2][4];
  #pragma unroll
  for (int cI = 0; cI < 2; ++cI) {
    int xc = tid + cI*256;
    float s = xc*0.25f - 0.375f;
    float jf = floorf(s); int j = (int)jf; float f = s - jf;
    float w[4] = { kcub(1.f+f), kcub(f), kcub(1.f-f), kcub(2.f-f) };
    float ws = 0.f;
    #pragma unroll
    for (int k = 0; k < 4; ++k) { int t = j-1+k; if (t < 0 || t > 127) w[k] = 0.f; ws += w[k]; }
    #pragma unroll
    for (int k = 0; k < 4; ++k) {
      wx[cI][k] = w[k]/ws;
      int t = j-1+k; tx[cI][k] = t < 0 ? 0 : (t > 127 ? 127 : t);
    }
  }

  auto rowdot = [&](int cI, int absrow) -> float {
    int rr = absrow < 0 ? 0 : (absrow > 127 ? 127 : absrow);
    const float* rp = rows + (rr - r0)*128;
    return wx[cI][0]*rp[tx[cI][0]] + wx[cI][1]*rp[tx[cI][1]]
         + wx[cI][2]*rp[tx[cI][2]] + wx[cI][3]*rp[tx[cI][3]];
  };

  int base = slab*16;
  float a0 = rowdot(0, base-2), a1 = rowdot(0, base-1), a2 = rowdot(0, base),   a3 = rowdot(0, base+1);
  float b0 = rowdot(1, base-2), b1 = rowdot(1, base-1), b2 = rowdot(1, base),   b3 = rowdot(1, base+1);

  for (int m = 0; m < 16; ++m) {
    float na  = rowdot(0, base + m + 2);
    float nb2 = rowdot(1, base + m + 2);
    int y0 = m*4;
    {
      float w0 = wyt[y0][0],   w1 = wyt[y0][1],   w2 = wyt[y0][2],   w3 = wyt[y0][3];
      size_t ob = ((size_t)(slab*64 + y0))*512;
      dst[ob + tid]       = w0*a0 + w1*a1 + w2*a2 + w3*a3;
      dst[ob + tid + 256] = w0*b0 + w1*b1 + w2*b2 + w3*b3;
    }
    {
      float w0 = wyt[y0+1][0], w1 = wyt[y0+1][1], w2 = wyt[y0+1][2], w3 = wyt[y0+1][3];
      size_t ob = ((size_t)(slab*64 + y0 + 1))*512;
      dst[ob + tid]       = w0*a0 + w1*a1 + w2*a2 + w3*a3;
      dst[ob + tid + 256] = w0*b0 + w1*b1 + w2*b2 + w3*b3;
    }
    {
      float w0 = wyt[y0+2][0], w1 = wyt[y0+2][1], w2 = wyt[y0+2][2], w3 = wyt[y0+2][3];
      size_t ob = ((size_t)(slab*64 + y0 + 2))*512;
      dst[ob + tid]       = w0*a1 + w1*a2 + w2*a3 + w3*na;
      dst[ob + tid + 256] = w0*b1 + w1*b2 + w2*b3 + w3*nb2;
    }
    {
      float w0 = wyt[y0+3][0], w1 = wyt[y0+3][1], w2 = wyt[y0+3][2], w3 = wyt[y0+3][3];
      size_t ob = ((size_t)(slab*64 + y0 + 3))*512;
      dst[ob + tid]       = w0*a1 + w1*a2 + w2*a3 + w3*na;
      dst[ob + tid + 256] = w0*b1 + w1*b2 + w2*b3 + w3*nb2;
    }
    a0 = a1; a1 = a2; a2 = a3; a3 = na;
    b0 = b1; b1 = b2; b2 = b3; b3 = nb2;
  }
}

// =====================================================================================
extern "C" void kernel_launch(void* const* d_in, const int* in_sizes, int n_in,
                              void* d_out, int out_size, void* d_ws, size_t ws_size,
                              hipStream_t stream) {
  (void)in_sizes; (void)n_in; (void)out_size; (void)ws_size;
  const float* x    = (const float*)d_in[0];
  const float* w1   = (const float*)d_in[1];
  const float* b1   = (const float*)d_in[2];
  const float* w2   = (const float*)d_in[3];
  const float* b2   = (const float*)d_in[4];
  const float* ln1g = (const float*)d_in[5];
  const float* ln1b = (const float*)d_in[6];
  const float* ln2g = (const float*)d_in[7];
  const float* ln2b = (const float*)d_in[8];
  const float* prot = (const float*)d_in[9];
  float* out = (float*)d_out;
  char* ws = (char*)d_ws;

  // workspace: 10.3 MB
  f16*   w1h  = (f16*)(ws + 0);                  //   131072 B
  f16*   w2h  = (f16*)(ws + 131072);             //   131072 B
  f16*   prth = (f16*)(ws + 262144);             //    98304 B (192x256 fp16)
  float* outs = (float*)(ws + 360448);           //  9961472 B  [8][19][16384] f32

  k_prep  <<<dim3(704),  dim3(64),  0, stream>>>(w1, w2, prot, w1h, w2h, prth);
  k_fused <<<dim3(1024), dim3(512), 0, stream>>>(x, w1h, b1, w2h, b2,
                                                 ln1g, ln1b, prth, ln2g, ln2b, outs);
  k_resize<<<dim3(1216), dim3(256), 0, stream>>>(outs, out);
}

// Round 5
// 352.667 us; speedup vs baseline: 1.3055x; 1.1385x over previous
//
#include <hip/hip_runtime.h>
#include <hip/hip_fp16.h>

// DeepLabV3 prototype-segmentation head, MI355X / gfx950.
// Round 5: fused kernel + (1) As transpose-write conflict fix (extra (row>>2) XOR),
// (2) pre-swizzled weight/proto images staged via global_load_lds (double-buffered Bs,
// issued before MFMA, drained at tail barrier), (3) x prefetch into ping-pong VGPRs
// with raw (non-vmcnt-draining) pre-MFMA barrier.
// Pipeline: prep(images) -> fused(conv1->relu->conv2->W-L2->LN256->L2->protoGEMM->max->LN19) -> resize.

typedef _Float16 f16;
typedef _Float16 f16x4 __attribute__((ext_vector_type(4)));
typedef _Float16 f16x8 __attribute__((ext_vector_type(8)));
typedef float    f32x16 __attribute__((ext_vector_type(16)));

#define HW2   16384   // 128*128 pixels per image
#define NCLS  19

// ---------------- LDS swizzles ----------------
// As (x tile) 128B rows: XOR slot with (row&7)^((row>>2)&7):
//  - transpose-writes (rows 4*pg+rr) spread over 8 slots  (was 16-way conflict)
//  - MFMA reads (consecutive rows) remain bijective per 8 rows
__device__ __forceinline__ int swzA(int row, int b) {
  return row*128 + ((((b >> 4) ^ (row & 7) ^ ((row >> 2) & 7)) << 4) | (b & 15));
}
// Bs (weights/protos) 128B rows: XOR slot with row&7 — must match k_prep's images
__device__ __forceinline__ int swzB(int row, int b) {
  return row*128 + ((((b >> 4) ^ (row & 7)) << 4) | (b & 15));
}
__device__ __forceinline__ int swz512(int row, int b) {           // 512B rows
  return row*512 + ((((b >> 4) ^ (row & 31)) << 4) | (b & 15));
}

// async global->LDS, 16B per lane; dst is wave-uniform base (HW adds lane*16)
__device__ __forceinline__ void gload16(const char* g, char* l) {
  __builtin_amdgcn_global_load_lds(
      (const __attribute__((address_space(1))) void*)g,
      (__attribute__((address_space(3))) void*)l, 16, 0, 0);
}

// =====================================================================================
// K0: prep — build pre-swizzled fp16 LDS images:
//   w1i/w2i: 4 chunks x [256 o][128 B]   (chunk cc holds c = cc*64..cc*64+63, swzB rows)
//   pri:     4 chunks x [192 r][128 B]   (l2-normalized prototypes, rows 190/191 zero)
// grid 704 x 64
// =====================================================================================
__global__ void k_prep(const float* __restrict__ w1, const float* __restrict__ w2,
                       const float* __restrict__ protos,
                       char* __restrict__ w1i, char* __restrict__ w2i, char* __restrict__ pri)
{
  int b = blockIdx.x, l = threadIdx.x;
  int cc = l >> 4, sw = (l >> 1) & 7, tb = (l & 1) * 4;   // each thread: 4 consecutive halfwords
  if (b < 512) {
    int o = b & 255;
    const float* src = (b < 256) ? (w1 + (size_t)o*256) : (w2 + (size_t)o*256);
    char* img = (b < 256) ? w1i : w2i;
    int c0 = cc*64 + ((sw ^ (o & 7)) << 3) + tb;          // inverse-swizzled source
    float4 v = *(const float4*)(src + c0);
    f16x4 h = { (f16)v.x, (f16)v.y, (f16)v.z, (f16)v.w };
    *(f16x4*)(img + cc*32768 + o*128 + sw*16 + tb*2) = h;
  } else {
    int r = b - 512;                                      // 0..191
    char* dst = pri + cc*24576 + r*128 + sw*16 + tb*2;
    if (r < 190) {
      float s = 0.f;
      #pragma unroll
      for (int j = 0; j < 4; ++j) { float v = protos[(size_t)r*256 + l + 64*j]; s += v*v; }
      #pragma unroll
      for (int m = 1; m < 64; m <<= 1) s += __shfl_xor(s, m);
      float sc = 1.f / fmaxf(sqrtf(s), 1e-12f);
      int c0 = cc*64 + ((sw ^ (r & 7)) << 3) + tb;
      float4 v = *(const float4*)(protos + (size_t)r*256 + c0);
      f16x4 h = { (f16)(v.x*sc), (f16)(v.y*sc), (f16)(v.z*sc), (f16)(v.w*sc) };
      *(f16x4*)dst = h;
    } else {
      f16x4 z = { (f16)0.f, (f16)0.f, (f16)0.f, (f16)0.f };
      *(f16x4*)dst = z;
    }
  }
}

// =====================================================================================
// K1: FUSED row kernel. Block = (image b, row pt): 128 pixels x all channels.
// 512 thr (8 waves). LDS 144 KB -> 1 block/CU.
//   As  @0      16KB [128 p][64 c]  x chunk (swzA)      | later nbuf/Lg/Lb | masks
//   Bs0 @16384  32KB  weight/proto chunk (swzB, even)   | masks
//   Bs1 @49152  32KB  weight/proto chunk (swzB, odd)    | masks
//   H   @81920  64KB [128 p][256]  h1 / h2 / c (swz512) | masks tail
//   masks @0    96KB [192 j][128 p] f32 (everything above dead)
//   Os @98304   9.5KB [19][128] f32
// =====================================================================================
__global__ void __launch_bounds__(512, 1) k_fused(
    const float* __restrict__ xf,
    const char* __restrict__ w1i, const float* __restrict__ b1g,
    const char* __restrict__ w2i, const float* __restrict__ b2g,
    const float* __restrict__ ln1g, const float* __restrict__ ln1b,
    const char* __restrict__ pri, const float* __restrict__ ln2g, const float* __restrict__ ln2b,
    float* __restrict__ outs)
{
  __shared__ char smem[147456];
  char* As  = smem;
  char* Bs0 = smem + 16384;
  char* Bs1 = smem + 49152;
  char* H   = smem + 81920;
  float* nbuf = (float*)smem;             // [2][256] f32 (W-L2 partials)
  float* Lg   = (float*)(smem + 4096);
  float* Lb   = (float*)(smem + 5120);
  float* Os   = (float*)(smem + 98304);   // [19][128]

  int bid = blockIdx.x;
  int b = bid >> 7, pt = bid & 127;
  int tid = threadIdx.x, lane = tid & 63, wid = tid >> 6;
  int hi = lane >> 5, l31 = lane & 31;
  int wp = wid >> 2, wn = wid & 3;        // conv wave grid: 2p x 4o

  // x staging mapping: thread = (cg 0..15, pg 0..31); 4x4 register transpose
  int cg = tid >> 5, pg = tid & 31;
  const float* xbase = xf + (size_t)b*256*HW2 + (size_t)(cg*4)*HW2 + pt*128 + pg*4;

  float4 xr[2][4];

  // ---------------- prologue: w1 chunk0 -> Bs0 (async), x chunk0 -> regs ----------------
  #pragma unroll
  for (int i = 0; i < 4; ++i) {
    int off = wid*4096 + i*1024;
    gload16(w1i + off + lane*16, Bs0 + off);
  }
  #pragma unroll
  for (int j = 0; j < 4; ++j) xr[0][j] = *(const float4*)(xbase + (size_t)j*HW2);
  __syncthreads();                        // drains gload + x loads

  f32x16 acc[2][2];
  #pragma unroll
  for (int m = 0; m < 2; ++m)
    #pragma unroll
    for (int n = 0; n < 2; ++n)
      #pragma unroll
      for (int r = 0; r < 16; ++r) acc[m][n][r] = 0.f;

  // ================= conv1: h1[128p][256o] = relu(X * W1^T + b1) =================
  #pragma unroll
  for (int cc = 0; cc < 4; ++cc) {
    char* Bcur = (cc & 1) ? Bs1 : Bs0;
    char* Bnxt = (cc & 1) ? Bs0 : Bs1;
    if (cc < 3) {                          // issue next-chunk loads first (overlap MFMA)
      #pragma unroll
      for (int i = 0; i < 4; ++i) {
        int off = wid*4096 + i*1024;
        gload16(w1i + (cc+1)*32768 + off + lane*16, Bnxt + off);
      }
      #pragma unroll
      for (int j = 0; j < 4; ++j)
        xr[(cc+1)&1][j] = *(const float4*)(xbase + (size_t)((cc+1)*64 + j)*HW2);
    }
    { // As <- 4x4 register transpose of xr[cc&1] (swzA: conflict-free writes)
      float4 v0 = xr[cc&1][0], v1 = xr[cc&1][1], v2 = xr[cc&1][2], v3 = xr[cc&1][3];
      f16x4 h;
      h = f16x4{(f16)v0.x,(f16)v1.x,(f16)v2.x,(f16)v3.x}; *(f16x4*)(As + swzA(pg*4+0, cg*8)) = h;
      h = f16x4{(f16)v0.y,(f16)v1.y,(f16)v2.y,(f16)v3.y}; *(f16x4*)(As + swzA(pg*4+1, cg*8)) = h;
      h = f16x4{(f16)v0.z,(f16)v1.z,(f16)v2.z,(f16)v3.z}; *(f16x4*)(As + swzA(pg*4+2, cg*8)) = h;
      h = f16x4{(f16)v0.w,(f16)v1.w,(f16)v2.w,(f16)v3.w}; *(f16x4*)(As + swzA(pg*4+3, cg*8)) = h;
    }
    // raw barrier: LDS writes visible, but keep vmcnt (next-chunk loads) in flight
    asm volatile("s_waitcnt lgkmcnt(0)" ::: "memory");
    __builtin_amdgcn_sched_barrier(0);
    __builtin_amdgcn_s_barrier();
    #pragma unroll
    for (int kk = 0; kk < 4; ++kk) {
      int byteK = kk*32 + hi*16;
      f16x8 a0 = *(const f16x8*)(As + swzA(wp*64 +      l31, byteK));
      f16x8 a1 = *(const f16x8*)(As + swzA(wp*64 + 32 + l31, byteK));
      f16x8 b0 = *(const f16x8*)(Bcur + swzB(wn*64 +      l31, byteK));
      f16x8 b1 = *(const f16x8*)(Bcur + swzB(wn*64 + 32 + l31, byteK));
      acc[0][0] = __builtin_amdgcn_mfma_f32_32x32x16_f16(a0, b0, acc[0][0], 0, 0, 0);
      acc[0][1] = __builtin_amdgcn_mfma_f32_32x32x16_f16(a0, b1, acc[0][1], 0, 0, 0);
      acc[1][0] = __builtin_amdgcn_mfma_f32_32x32x16_f16(a1, b0, acc[1][0], 0, 0, 0);
      acc[1][1] = __builtin_amdgcn_mfma_f32_32x32x16_f16(a1, b1, acc[1][1], 0, 0, 0);
    }
    __syncthreads();                       // drains next-chunk gload/x-loads; frees As/Bcur
  }

  // prefetch w2 chunk0 -> Bs0 under the conv1 epilogue (Bs0 free: all waves past loop)
  #pragma unroll
  for (int i = 0; i < 4; ++i) {
    int off = wid*4096 + i*1024;
    gload16(w2i + off + lane*16, Bs0 + off);
  }
  // epilogue: bias + relu -> H fp16 [128p][256o]
  #pragma unroll
  for (int n = 0; n < 2; ++n) {
    int o = wn*64 + n*32 + l31;
    float bv = b1g[o];
    #pragma unroll
    for (int m = 0; m < 2; ++m)
      #pragma unroll
      for (int r = 0; r < 16; ++r) {
        int p = wp*64 + m*32 + (r & 3) + 8*(r >> 2) + 4*hi;   // D layout (m74/m101)
        *(f16*)(H + swz512(p, o*2)) = (f16)fmaxf(acc[m][n][r] + bv, 0.f);
      }
  }
  __syncthreads();                         // H visible + w2(0) drained

  // ================= conv2: h2[128p][256o] = h1 * W2^T + b2 =================
  #pragma unroll
  for (int m = 0; m < 2; ++m)
    #pragma unroll
    for (int n = 0; n < 2; ++n)
      #pragma unroll
      for (int r = 0; r < 16; ++r) acc[m][n][r] = 0.f;

  #pragma unroll
  for (int cc = 0; cc < 4; ++cc) {
    char* Bcur = (cc & 1) ? Bs1 : Bs0;
    char* Bnxt = (cc & 1) ? Bs0 : Bs1;
    if (cc < 3) {
      #pragma unroll
      for (int i = 0; i < 4; ++i) {
        int off = wid*4096 + i*1024;
        gload16(w2i + (cc+1)*32768 + off + lane*16, Bnxt + off);
      }
    }
    #pragma unroll
    for (int kk = 0; kk < 4; ++kk) {
      int byteC = cc*128 + kk*32 + hi*16;
      int byteK = kk*32 + hi*16;
      f16x8 a0 = *(const f16x8*)(H + swz512(wp*64 +      l31, byteC));
      f16x8 a1 = *(const f16x8*)(H + swz512(wp*64 + 32 + l31, byteC));
      f16x8 b0 = *(const f16x8*)(Bcur + swzB(wn*64 +      l31, byteK));
      f16x8 b1 = *(const f16x8*)(Bcur + swzB(wn*64 + 32 + l31, byteK));
      acc[0][0] = __builtin_amdgcn_mfma_f32_32x32x16_f16(a0, b0, acc[0][0], 0, 0, 0);
      acc[0][1] = __builtin_amdgcn_mfma_f32_32x32x16_f16(a0, b1, acc[0][1], 0, 0, 0);
      acc[1][0] = __builtin_amdgcn_mfma_f32_32x32x16_f16(a1, b0, acc[1][0], 0, 0, 0);
      acc[1][1] = __builtin_amdgcn_mfma_f32_32x32x16_f16(a1, b1, acc[1][1], 0, 0, 0);
    }
    __syncthreads();                       // drains next-chunk gload; frees Bcur
  }

  // prefetch proto chunk0 -> Bs0 under the W-L2/LN phases
  #pragma unroll
  for (int i = 0; i < 3; ++i) {
    int off = wid*3072 + i*1024;
    gload16(pri + off + lane*16, Bs0 + off);
  }

  // ---- bias2 + W-axis L2 (norm over the 128 pixels, per channel o) ----
  float sn[2];
  #pragma unroll
  for (int n = 0; n < 2; ++n) {
    int o = wn*64 + n*32 + l31;
    float bv = b2g[o];
    float s = 0.f;
    #pragma unroll
    for (int m = 0; m < 2; ++m)
      #pragma unroll
      for (int r = 0; r < 16; ++r) { acc[m][n][r] += bv; s += acc[m][n][r]*acc[m][n][r]; }
    s += __shfl_xor(s, 32);                // combine hi halves (same o, disjoint p)
    sn[n] = s;
  }
  if (lane < 32) {
    nbuf[wp*256 + wn*64 +      lane] = sn[0];
    nbuf[wp*256 + wn*64 + 32 + lane] = sn[1];
  }
  if (tid < 256) { Lg[tid] = ln1g[tid]; Lb[tid] = ln1b[tid]; }
  __syncthreads();
  #pragma unroll
  for (int n = 0; n < 2; ++n) {
    int o = wn*64 + n*32 + l31;
    float tot = nbuf[o] + nbuf[256 + o];
    float sc = 1.f / fmaxf(sqrtf(tot), 1e-12f);
    #pragma unroll
    for (int m = 0; m < 2; ++m)
      #pragma unroll
      for (int r = 0; r < 16; ++r) {
        int p = wp*64 + m*32 + (r & 3) + 8*(r >> 2) + 4*hi;
        *(f16*)(H + swz512(p, o*2)) = (f16)(acc[m][n][r]*sc);
      }
  }
  __syncthreads();

  // ---- per-pixel LayerNorm(256) + l2-normalize (4 lanes per pixel, self-RMW only) ----
  {
    int p = tid >> 2, q = tid & 3;
    f16x8 hreg[8];
    float sh = 0.f;
    #pragma unroll
    for (int j = 0; j < 8; ++j) {
      hreg[j] = *(const f16x8*)(H + swz512(p, q*128 + j*16));
      #pragma unroll
      for (int e = 0; e < 8; ++e) sh += (float)hreg[j][e];
    }
    sh += __shfl_xor(sh, 1); sh += __shfl_xor(sh, 2);
    float mu = sh * (1.f/256.f);
    float sv = 0.f;
    #pragma unroll
    for (int j = 0; j < 8; ++j)
      #pragma unroll
      for (int e = 0; e < 8; ++e) { float d = (float)hreg[j][e] - mu; sv += d*d; }
    sv += __shfl_xor(sv, 1); sv += __shfl_xor(sv, 2);
    float rstd = rsqrtf(sv*(1.f/256.f) + 1e-5f);
    float s2 = 0.f; f16x8 creg[8];
    #pragma unroll
    for (int j = 0; j < 8; ++j) {
      int ob = q*64 + j*8;
      #pragma unroll
      for (int e = 0; e < 8; ++e) {
        float c = ((float)hreg[j][e] - mu)*rstd*Lg[ob+e] + Lb[ob+e];
        s2 += c*c; creg[j][e] = (f16)c;
      }
    }
    s2 += __shfl_xor(s2, 1); s2 += __shfl_xor(s2, 2);
    float scale = 1.f / fmaxf(sqrtf(s2), 1e-12f);
    #pragma unroll
    for (int j = 0; j < 8; ++j) {
      f16x8 w;
      #pragma unroll
      for (int e = 0; e < 8; ++e) w[e] = (f16)((float)creg[j][e]*scale);
      *(f16x8*)(H + swz512(p, q*128 + j*16)) = w;
    }
  }
  __syncthreads();                         // c visible for proto GEMM

  // ================= proto GEMM: masks[192 j][128 p] = c x protos^T =================
  int wj = wid & 1, wp2 = wid >> 1;        // 2 j-waves x 4 p-waves
  f32x16 am[3];
  #pragma unroll
  for (int n = 0; n < 3; ++n)
    #pragma unroll
    for (int r = 0; r < 16; ++r) am[n][r] = 0.f;

  #pragma unroll
  for (int cci = 0; cci < 4; ++cci) {
    char* Bcur = (cci & 1) ? Bs1 : Bs0;
    char* Bnxt = (cci & 1) ? Bs0 : Bs1;
    if (cci < 3) {
      #pragma unroll
      for (int i = 0; i < 3; ++i) {
        int off = wid*3072 + i*1024;
        gload16(pri + (cci+1)*24576 + off + lane*16, Bnxt + off);
      }
    }
    #pragma unroll
    for (int kk = 0; kk < 4; ++kk) {
      int byteC = cci*128 + kk*32 + hi*16;
      int byteK = kk*32 + hi*16;
      f16x8 af = *(const f16x8*)(H + swz512(wp2*32 + l31, byteC));
      #pragma unroll
      for (int n = 0; n < 3; ++n) {
        f16x8 bf = *(const f16x8*)(Bcur + swzB(wj*96 + n*32 + l31, byteK));
        am[n] = __builtin_amdgcn_mfma_f32_32x32x16_f16(af, bf, am[n], 0, 0, 0);
      }
    }
    __syncthreads();
  }

  // masks scatter: [192 j][128 p] f32 @ smem+0 (As/Bs/H all dead)
  #pragma unroll
  for (int n = 0; n < 3; ++n) {
    int j = wj*96 + n*32 + l31;
    #pragma unroll
    for (int r = 0; r < 16; ++r) {
      int p = wp2*32 + (r & 3) + 8*(r >> 2) + 4*hi;
      *(float*)(smem + swz512(j, p*4)) = am[n][r];
    }
  }
  __syncthreads();

  // ---- max over 10 prototypes + LayerNorm(19) (4 lanes per pixel) ----
  {
    int pp = tid >> 2, ql = tid & 3;
    float mx[5]; float ssum = 0.f;
    #pragma unroll
    for (int ki = 0; ki < 5; ++ki) {
      int k = ql + 4*ki;
      float m = 0.f;
      if (k < NCLS) {
        m = -1e30f;
        #pragma unroll
        for (int mm = 0; mm < 10; ++mm)
          m = fmaxf(m, *(const float*)(smem + swz512(k*10 + mm, pp*4)));
        ssum += m;
      }
      mx[ki] = m;
    }
    ssum += __shfl_xor(ssum, 1); ssum += __shfl_xor(ssum, 2);
    float mu2 = ssum * (1.f/19.f);
    float sv2 = 0.f;
    #pragma unroll
    for (int ki = 0; ki < 5; ++ki) {
      int k = ql + 4*ki;
      if (k < NCLS) { float d = mx[ki]-mu2; sv2 += d*d; }
    }
    sv2 += __shfl_xor(sv2, 1); sv2 += __shfl_xor(sv2, 2);
    float rstd2 = rsqrtf(sv2*(1.f/19.f) + 1e-5f);
    #pragma unroll
    for (int ki = 0; ki < 5; ++ki) {
      int k = ql + 4*ki;
      if (k < NCLS) Os[k*128 + pp] = (mx[ki]-mu2)*rstd2*ln2g[k] + ln2b[k];
    }
  }
  __syncthreads();
  for (int idx = tid; idx < NCLS*128; idx += 512) {
    int k = idx >> 7, pp = idx & 127;
    outs[((size_t)b*NCLS + k)*HW2 + pt*128 + pp] = Os[idx];
  }
}

// =====================================================================================
// K2: bicubic 4x upsample (jax cubic: Keys a=-0.5, half-pixel, border renormalization).
// grid 1216 = (8*19 ch) * 8 y-slabs; 256 thr (each owns 2 output columns).
// =====================================================================================
__device__ __forceinline__ float kcub(float t) {       // t >= 0
  if (t >= 2.f) return 0.f;
  if (t >= 1.f) return ((-0.5f*t + 2.5f)*t - 4.f)*t + 2.f;
  return ((1.5f*t - 2.5f)*t)*t + 1.f;
}

__global__ void __launch_bounds__(256) k_resize(const float* __restrict__ outs,
                                                float* __restrict__ out)
{
  int ch = blockIdx.x >> 3, slab = blockIdx.x & 7;
  const float* src = outs + (size_t)ch*HW2;
  float* dst = out + (size_t)ch*262144;
  __shared__ float rows[20*128];
  __shared__ float wyt[64][4];
  int tid = threadIdx.x;

  int r0 = slab*16 - 2; if (r0 < 0) r0 = 0;
  int r1 = slab*16 + 17; if (r1 > 127) r1 = 127;
  int nr = r1 - r0 + 1;
  for (int idx = tid; idx < nr*128; idx += 256) rows[idx] = src[r0*128 + idx];

  if (tid < 64) {
    int y = slab*64 + tid;
    float s = y*0.25f - 0.375f;
    float jf = floorf(s); int j = (int)jf; float f = s - jf;
    float w[4] = { kcub(1.f+f), kcub(f), kcub(1.f-f), kcub(2.f-f) };
    float ws = 0.f;
    #pragma unroll
    for (int k = 0; k < 4; ++k) { int t = j-1+k; if (t < 0 || t > 127) w[k] = 0.f; ws += w[k]; }
    float inv = 1.f/ws;
    #pragma unroll
    for (int k = 0; k < 4; ++k) wyt[tid][k] = w[k]*inv;
  }
  __syncthreads();

  float wx[2][4]; int tx[2][4];
  #pragma unroll
  for (int cI = 0; cI < 2; ++cI) {
    int xc = tid + cI*256;
    float s = xc*0.25f - 0.375f;
    float jf = floorf(s); int j = (int)jf; float f = s - jf;
    float w[4] = { kcub(1.f+f), kcub(f), kcub(1.f-f), kcub(2.f-f) };
    float ws = 0.f;
    #pragma unroll
    for (int k = 0; k < 4; ++k) { int t = j-1+k; if (t < 0 || t > 127) w[k] = 0.f; ws += w[k]; }
    #pragma unroll
    for (int k = 0; k < 4; ++k) {
      wx[cI][k] = w[k]/ws;
      int t = j-1+k; tx[cI][k] = t < 0 ? 0 : (t > 127 ? 127 : t);
    }
  }

  auto rowdot = [&](int cI, int absrow) -> float {
    int rr = absrow < 0 ? 0 : (absrow > 127 ? 127 : absrow);
    const float* rp = rows + (rr - r0)*128;
    return wx[cI][0]*rp[tx[cI][0]] + wx[cI][1]*rp[tx[cI][1]]
         + wx[cI][2]*rp[tx[cI][2]] + wx[cI][3]*rp[tx[cI][3]];
  };

  int base = slab*16;
  float a0 = rowdot(0, base-2), a1 = rowdot(0, base-1), a2 = rowdot(0, base),   a3 = rowdot(0, base+1);
  float b0 = rowdot(1, base-2), b1 = rowdot(1, base-1), b2 = rowdot(1, base),   b3 = rowdot(1, base+1);

  for (int m = 0; m < 16; ++m) {
    float na  = rowdot(0, base + m + 2);
    float nb2 = rowdot(1, base + m + 2);
    int y0 = m*4;
    {
      float w0 = wyt[y0][0],   w1 = wyt[y0][1],   w2 = wyt[y0][2],   w3 = wyt[y0][3];
      size_t ob = ((size_t)(slab*64 + y0))*512;
      dst[ob + tid]       = w0*a0 + w1*a1 + w2*a2 + w3*a3;
      dst[ob + tid + 256] = w0*b0 + w1*b1 + w2*b2 + w3*b3;
    }
    {
      float w0 = wyt[y0+1][0], w1 = wyt[y0+1][1], w2 = wyt[y0+1][2], w3 = wyt[y0+1][3];
      size_t ob = ((size_t)(slab*64 + y0 + 1))*512;
      dst[ob + tid]       = w0*a0 + w1*a1 + w2*a2 + w3*a3;
      dst[ob + tid + 256] = w0*b0 + w1*b1 + w2*b2 + w3*b3;
    }
    {
      float w0 = wyt[y0+2][0], w1 = wyt[y0+2][1], w2 = wyt[y0+2][2], w3 = wyt[y0+2][3];
      size_t ob = ((size_t)(slab*64 + y0 + 2))*512;
      dst[ob + tid]       = w0*a1 + w1*a2 + w2*a3 + w3*na;
      dst[ob + tid + 256] = w0*b1 + w1*b2 + w2*b3 + w3*nb2;
    }
    {
      float w0 = wyt[y0+3][0], w1 = wyt[y0+3][1], w2 = wyt[y0+3][2], w3 = wyt[y0+3][3];
      size_t ob = ((size_t)(slab*64 + y0 + 3))*512;
      dst[ob + tid]       = w0*a1 + w1*a2 + w2*a3 + w3*na;
      dst[ob + tid + 256] = w0*b1 + w1*b2 + w2*b3 + w3*nb2;
    }
    a0 = a1; a1 = a2; a2 = a3; a3 = na;
    b0 = b1; b1 = b2; b2 = b3; b3 = nb2;
  }
}

// =====================================================================================
extern "C" void kernel_launch(void* const* d_in, const int* in_sizes, int n_in,
                              void* d_out, int out_size, void* d_ws, size_t ws_size,
                              hipStream_t stream) {
  (void)in_sizes; (void)n_in; (void)out_size; (void)ws_size;
  const float* x    = (const float*)d_in[0];
  const float* w1   = (const float*)d_in[1];
  const float* b1   = (const float*)d_in[2];
  const float* w2   = (const float*)d_in[3];
  const float* b2   = (const float*)d_in[4];
  const float* ln1g = (const float*)d_in[5];
  const float* ln1b = (const float*)d_in[6];
  const float* ln2g = (const float*)d_in[7];
  const float* ln2b = (const float*)d_in[8];
  const float* prot = (const float*)d_in[9];
  float* out = (float*)d_out;
  char* ws = (char*)d_ws;

  // workspace: 10.3 MB
  char*  w1i  = ws + 0;                          //   131072 B (4 chunk-images)
  char*  w2i  = ws + 131072;                     //   131072 B
  char*  pri  = ws + 262144;                     //    98304 B (4 chunk-images, 192 rows)
  float* outs = (float*)(ws + 360448);           //  9961472 B  [8][19][16384] f32

  k_prep  <<<dim3(704),  dim3(64),  0, stream>>>(w1, w2, prot, w1i, w2i, pri);
  k_fused <<<dim3(1024), dim3(512), 0, stream>>>(x, w1i, b1, w2i, b2,
                                                 ln1g, ln1b, pri, ln2g, ln2b, outs);
  k_resize<<<dim3(1216), dim3(256), 0, stream>>>(outs, out);
}